// Round 1
// baseline (475.351 us; speedup 1.0000x reference)
//
#include <hip/hip_runtime.h>

// ---------------- types / helpers ----------------
typedef __attribute__((ext_vector_type(8))) short short8v;   // 8 bf16 (4 VGPR)
typedef __attribute__((ext_vector_type(4))) float float4v;   // MFMA acc

__device__ __forceinline__ unsigned short f2bf(float f) {
  union { float f; unsigned u; } a; a.f = f;
  unsigned r = a.u + 0x7fffu + ((a.u >> 16) & 1u);   // RNE
  return (unsigned short)(r >> 16);
}
__device__ __forceinline__ float2 up2(unsigned u) {  // packed 2xbf16 -> 2 floats
  union { unsigned u; float f; } a, b;
  a.u = u << 16; b.u = u & 0xffff0000u;
  return make_float2(a.f, b.f);
}

__device__ __forceinline__ void gl_lds16(const void* g, void* l) {
  __builtin_amdgcn_global_load_lds(
      (const __attribute__((address_space(1))) void*)g,
      (__attribute__((address_space(3))) void*)l, 16, 0, 0);
}

// ---------------- K0: fp32 -> bf16 weight convert ----------------
__global__ __launch_bounds__(256) void wconv(const float* __restrict__ src,
                                             unsigned short* __restrict__ dst, int n) {
  int i = (blockIdx.x * 256 + threadIdx.x) * 4;
  if (i < n) {
    float4 v = *(const float4*)(src + i);
    uint2 o;
    o.x = (unsigned)f2bf(v.x) | ((unsigned)f2bf(v.y) << 16);
    o.y = (unsigned)f2bf(v.z) | ((unsigned)f2bf(v.w) << 16);
    *(uint2*)(dst + i) = o;
  }
}

// ---------------- K1: groupnorm stats (one block per (b,g)) ----------------
__global__ __launch_bounds__(256) void gn_stats(const float* __restrict__ x,
                                                float2* __restrict__ stats) {
  int bg = blockIdx.x;                       // b*32+g
  const float* base = x + (size_t)bg * 65536; // 16 ch * 4096
  int tid = threadIdx.x;
  float s = 0.f, s2 = 0.f;
  for (int i = tid; i < 16384; i += 256) {
    float4 v = *(const float4*)(base + (size_t)i * 4);
    s  += v.x + v.y + v.z + v.w;
    s2 += v.x * v.x + v.y * v.y + v.z * v.z + v.w * v.w;
  }
  #pragma unroll
  for (int off = 32; off > 0; off >>= 1) {
    s  += __shfl_down(s, off);
    s2 += __shfl_down(s2, off);
  }
  __shared__ float red[8];
  int w = tid >> 6, l = tid & 63;
  if (l == 0) { red[w] = s; red[w + 4] = s2; }
  __syncthreads();
  if (tid == 0) {
    float ts = red[0] + red[1] + red[2] + red[3];
    float t2 = red[4] + red[5] + red[6] + red[7];
    float mean = ts * (1.f / 65536.f);
    float var  = t2 * (1.f / 65536.f) - mean * mean;
    stats[bg] = make_float2(mean, rsqrtf(var + 1e-5f));
  }
}

// ---------------- K2: normalize + transpose -> h[b*n][c] bf16 ----------------
// grid (N/64, C/64, B), block (64,8)
__global__ __launch_bounds__(512) void norm_tr(const float* __restrict__ x,
                                               const float* __restrict__ nw,
                                               const float* __restrict__ nb,
                                               const float2* __restrict__ stats,
                                               unsigned short* __restrict__ h) {
  __shared__ float t[64][65];
  int n0 = blockIdx.x * 64, c0 = blockIdx.y * 64, b = blockIdx.z;
  int tx = threadIdx.x, ty = threadIdx.y;
  #pragma unroll
  for (int j = ty; j < 64; j += 8) {
    int c = c0 + j;
    float2 ms = stats[b * 32 + (c >> 4)];
    float v = x[((size_t)b * 512 + c) * 4096 + n0 + tx];
    t[j][tx] = (v - ms.x) * ms.y * nw[c] + nb[c];
  }
  __syncthreads();
  #pragma unroll
  for (int j = ty; j < 64; j += 8) {
    int n = n0 + j;
    h[((size_t)b * 4096 + n) * 512 + c0 + tx] = f2bf(t[tx][j]);
  }
}

// ---------------- GEMM core: 128x128 tile, K=512, bf16 MFMA 16x16x32 ----------
// A row-major [M][512], Bmat row-major [N][512] (acts as B^T). 256 thr = 4 waves.
__device__ __forceinline__ void gemm_core(const unsigned short* __restrict__ A,
                                          const unsigned short* __restrict__ Bmat,
                                          unsigned short* As, unsigned short* Bs,
                                          int m0, int n0, float4v acc[4][4]) {
  int tid = threadIdx.x;
  int w = tid >> 6, l = tid & 63;
  int srow = w * 32 + (l >> 2);
  int scol = (l & 3) * 8;
  const unsigned short* pa0 = A + (size_t)(m0 + srow) * 512 + scol;
  const unsigned short* pa1 = pa0 + 16 * 512;
  const unsigned short* pb0 = Bmat + (size_t)(n0 + srow) * 512 + scol;
  const unsigned short* pb1 = pb0 + 16 * 512;
  unsigned short* lA0 = As + w * 1024;
  unsigned short* lA1 = As + w * 1024 + 512;
  unsigned short* lB0 = Bs + w * 1024;
  unsigned short* lB1 = Bs + w * 1024 + 512;
  int wrow = w >> 1, wcol = w & 1;
  const unsigned short* arp = As + (wrow * 64 + (l & 15)) * 32 + (l >> 4) * 8;
  const unsigned short* brp = Bs + (wcol * 64 + (l & 15)) * 32 + (l >> 4) * 8;

  for (int kt = 0; kt < 16; ++kt) {
    if (kt) __syncthreads();
    gl_lds16(pa0, lA0); gl_lds16(pa1, lA1);
    gl_lds16(pb0, lB0); gl_lds16(pb1, lB1);
    pa0 += 32; pa1 += 32; pb0 += 32; pb1 += 32;
    __syncthreads();
    short8v a[4], b[4];
    #pragma unroll
    for (int i = 0; i < 4; ++i) {
      a[i] = *(const short8v*)(arp + i * 16 * 32);
      b[i] = *(const short8v*)(brp + i * 16 * 32);
    }
    #pragma unroll
    for (int mi = 0; mi < 4; ++mi)
      #pragma unroll
      for (int ni = 0; ni < 4; ++ni)
        acc[mi][ni] = __builtin_amdgcn_mfma_f32_16x16x32_bf16(a[mi], b[ni], acc[mi][ni], 0, 0, 0);
  }
}

// ---------------- K3: qkv GEMM (M=65536, N=1536, K=512) -> bf16 ----------------
__global__ __launch_bounds__(256) void gemm_qkv(const unsigned short* __restrict__ h,
                                                const unsigned short* __restrict__ wq,
                                                const float* __restrict__ bias,
                                                unsigned short* __restrict__ outq) {
  __shared__ unsigned short As[128 * 32], Bs[128 * 32];
  float4v acc[4][4] = {};
  int m0 = blockIdx.x * 128, n0 = blockIdx.y * 128;
  gemm_core(h, wq, As, Bs, m0, n0, acc);
  int tid = threadIdx.x;
  int w = tid >> 6, l = tid & 63;
  int wrow = w >> 1, wcol = w & 1;
  #pragma unroll
  for (int mi = 0; mi < 4; ++mi) {
    #pragma unroll
    for (int ni = 0; ni < 4; ++ni) {
      int row = m0 + wrow * 64 + mi * 16 + (l >> 4) * 4;
      int col = n0 + wcol * 64 + ni * 16 + (l & 15);
      float bb = bias[col];
      #pragma unroll
      for (int j = 0; j < 4; ++j)
        outq[(size_t)(row + j) * 1536 + col] = f2bf(acc[mi][ni][j] + bb);
    }
  }
}

// ---------------- K4: per-position 8-head x 8-head attention ----------------
// block = 256 thr = 32 positions x 8 heads; k/v staged in LDS (stride 1032 = bank-safe)
__global__ __launch_bounds__(256) void attn_k(const unsigned short* __restrict__ qkv,
                                              unsigned short* __restrict__ o) {
  __shared__ unsigned short kvs[32][1032];   // k at [0,512), v at [520,1032)
  int tid = threadIdx.x;
  int p0 = blockIdx.x * 32;
  #pragma unroll
  for (int it = 0; it < 16; ++it) {
    int idx = it * 256 + tid;
    int p = idx >> 7, ch = idx & 127;       // 128 x 16B chunks of (k|v) per position
    uint4 v = *(const uint4*)(qkv + (size_t)(p0 + p) * 1536 + 512 + ch * 8);
    int j = ch * 8;
    int dstoff = (j < 512) ? j : (j + 8);
    *(uint4*)&kvs[p][dstoff] = v;
  }
  int pl = tid >> 3, hh = tid & 7;
  const uint4* qsrc = (const uint4*)(qkv + (size_t)(p0 + pl) * 1536 + hh * 64);
  float q[64];
  #pragma unroll
  for (int i = 0; i < 8; ++i) {
    uint4 u = qsrc[i];
    float2 t0 = up2(u.x), t1 = up2(u.y), t2 = up2(u.z), t3 = up2(u.w);
    q[i*8+0]=t0.x; q[i*8+1]=t0.y; q[i*8+2]=t1.x; q[i*8+3]=t1.y;
    q[i*8+4]=t2.x; q[i*8+5]=t2.y; q[i*8+6]=t3.x; q[i*8+7]=t3.y;
  }
  __syncthreads();
  float lg[8];
  #pragma unroll
  for (int g = 0; g < 8; ++g) {
    float s = 0.f;
    #pragma unroll
    for (int d8 = 0; d8 < 8; ++d8) {
      uint4 kk = *(const uint4*)&kvs[pl][g * 64 + d8 * 8];
      float2 k0 = up2(kk.x), k1 = up2(kk.y), k2 = up2(kk.z), k3 = up2(kk.w);
      s += q[d8*8+0]*k0.x + q[d8*8+1]*k0.y + q[d8*8+2]*k1.x + q[d8*8+3]*k1.y
         + q[d8*8+4]*k2.x + q[d8*8+5]*k2.y + q[d8*8+6]*k3.x + q[d8*8+7]*k3.y;
    }
    lg[g] = s * 0.125f;   // hd^-0.5
  }
  float mx = lg[0];
  #pragma unroll
  for (int g = 1; g < 8; ++g) mx = fmaxf(mx, lg[g]);
  float ssum = 0.f;
  #pragma unroll
  for (int g = 0; g < 8; ++g) { lg[g] = __expf(lg[g] - mx); ssum += lg[g]; }
  float inv = 1.f / ssum;
  #pragma unroll
  for (int g = 0; g < 8; ++g) lg[g] *= inv;
  float oa[64];
  #pragma unroll
  for (int i = 0; i < 64; ++i) oa[i] = 0.f;
  #pragma unroll
  for (int g = 0; g < 8; ++g) {
    float wg = lg[g];
    #pragma unroll
    for (int d8 = 0; d8 < 8; ++d8) {
      uint4 vv = *(const uint4*)&kvs[pl][520 + g * 64 + d8 * 8];
      float2 v0 = up2(vv.x), v1 = up2(vv.y), v2 = up2(vv.z), v3 = up2(vv.w);
      oa[d8*8+0] += wg*v0.x; oa[d8*8+1] += wg*v0.y;
      oa[d8*8+2] += wg*v1.x; oa[d8*8+3] += wg*v1.y;
      oa[d8*8+4] += wg*v2.x; oa[d8*8+5] += wg*v2.y;
      oa[d8*8+6] += wg*v3.x; oa[d8*8+7] += wg*v3.y;
    }
  }
  unsigned short* dst = o + (size_t)(p0 + pl) * 512 + hh * 64;
  #pragma unroll
  for (int i = 0; i < 8; ++i) {
    uint4 w_;
    w_.x = (unsigned)f2bf(oa[i*8+0]) | ((unsigned)f2bf(oa[i*8+1]) << 16);
    w_.y = (unsigned)f2bf(oa[i*8+2]) | ((unsigned)f2bf(oa[i*8+3]) << 16);
    w_.z = (unsigned)f2bf(oa[i*8+4]) | ((unsigned)f2bf(oa[i*8+5]) << 16);
    w_.w = (unsigned)f2bf(oa[i*8+6]) | ((unsigned)f2bf(oa[i*8+7]) << 16);
    *(uint4*)(dst + i * 8) = w_;
  }
}

// ---------------- K5: proj GEMM + residual + transposed write ----------------
// out[b][c][n] = x[b][c][n] + (o @ proj_w^T + pb)[b*4096+n][c]
__global__ __launch_bounds__(256) void gemm_proj(const unsigned short* __restrict__ o,
                                                 const unsigned short* __restrict__ wp,
                                                 const float* __restrict__ bias,
                                                 const float* __restrict__ x,
                                                 float* __restrict__ out) {
  __shared__ unsigned short As[128 * 32], Bs[128 * 32];
  __shared__ float es[4][16][68];
  float4v acc[4][4] = {};
  int m0 = blockIdx.x * 128, n0 = blockIdx.y * 128;
  gemm_core(o, wp, As, Bs, m0, n0, acc);
  int tid = threadIdx.x;
  int w = tid >> 6, l = tid & 63;
  int wrow = w >> 1, wcol = w & 1;
  int b = m0 >> 12;               // 128-row tile never straddles a batch
  #pragma unroll
  for (int mi = 0; mi < 4; ++mi) {
    int mbase = m0 + wrow * 64 + mi * 16;
    int nloc = mbase & 4095;
    #pragma unroll
    for (int ni = 0; ni < 4; ++ni)
      #pragma unroll
      for (int j = 0; j < 4; ++j)
        es[w][(l >> 4) * 4 + j][ni * 16 + (l & 15)] = acc[mi][ni][j];
    // same-wave LDS write->read; compiler inserts lgkmcnt waits
    int c = n0 + wcol * 64 + l;
    float bc = bias[c];
    const float* xr = x + ((size_t)b * 512 + c) * 4096 + nloc;
    float* orow = out + ((size_t)b * 512 + c) * 4096 + nloc;
    #pragma unroll
    for (int r4 = 0; r4 < 4; ++r4) {
      float4 xv = *(const float4*)(xr + r4 * 4);
      float4 ov;
      ov.x = xv.x + bc + es[w][r4 * 4 + 0][l];
      ov.y = xv.y + bc + es[w][r4 * 4 + 1][l];
      ov.z = xv.z + bc + es[w][r4 * 4 + 2][l];
      ov.w = xv.w + bc + es[w][r4 * 4 + 3][l];
      *(float4*)(orow + r4 * 4) = ov;
    }
    __syncthreads();   // es reused next mi by all waves? (per-wave buffer, but keep waves in step cheaply)
  }
}

// ---------------- launcher ----------------
extern "C" void kernel_launch(void* const* d_in, const int* in_sizes, int n_in,
                              void* d_out, int out_size, void* d_ws, size_t ws_size,
                              hipStream_t stream) {
  const float* x     = (const float*)d_in[0];
  const float* nw    = (const float*)d_in[1];
  const float* nb    = (const float*)d_in[2];
  const float* qkvw  = (const float*)d_in[3];
  const float* qkvb  = (const float*)d_in[4];
  const float* pw    = (const float*)d_in[5];
  const float* pb    = (const float*)d_in[6];
  float* out = (float*)d_out;
  char* ws = (char*)d_ws;

  const size_t OFF_WQ   = 4096;                       // stats: 512 * float2
  const size_t OFF_WP   = OFF_WQ + 1572864;           // qkv_w bf16: 1536*512*2
  const size_t OFF_H    = OFF_WP + 524288;            // proj_w bf16: 512*512*2
  const size_t OFF_QKV  = OFF_H + 67108864;           // h / o: 65536*512*2

  float2* stats          = (float2*)ws;
  unsigned short* wq_b   = (unsigned short*)(ws + OFF_WQ);
  unsigned short* wp_b   = (unsigned short*)(ws + OFF_WP);
  unsigned short* h      = (unsigned short*)(ws + OFF_H);    // reused as attention output o
  unsigned short* qkv    = (unsigned short*)(ws + OFF_QKV);

  wconv<<<768, 256, 0, stream>>>(qkvw, wq_b, 786432);
  wconv<<<256, 256, 0, stream>>>(pw,   wp_b, 262144);
  gn_stats<<<512, 256, 0, stream>>>(x, stats);
  norm_tr<<<dim3(64, 8, 16), dim3(64, 8), 0, stream>>>(x, nw, nb, stats, h);
  gemm_qkv<<<dim3(512, 12), 256, 0, stream>>>(h, wq_b, qkvb, qkv);
  attn_k<<<2048, 256, 0, stream>>>(qkv, h);
  gemm_proj<<<dim3(512, 4), 256, 0, stream>>>(h, wp_b, pb, x, out);
}

// Round 2
// 427.975 us; speedup vs baseline: 1.1107x; 1.1107x over previous
//
#include <hip/hip_runtime.h>

// ---------------- types / helpers ----------------
typedef __attribute__((ext_vector_type(8))) short short8v;   // 8 bf16 (4 VGPR)
typedef __attribute__((ext_vector_type(4))) float float4v;   // MFMA acc
typedef unsigned short ushortT;

__device__ __forceinline__ unsigned short f2bf(float f) {
  union { float f; unsigned u; } a; a.f = f;
  unsigned r = a.u + 0x7fffu + ((a.u >> 16) & 1u);   // RNE
  return (unsigned short)(r >> 16);
}
__device__ __forceinline__ float2 up2(unsigned u) {  // packed 2xbf16 -> 2 floats
  union { unsigned u; float f; } a, b;
  a.u = u << 16; b.u = u & 0xffff0000u;
  return make_float2(a.f, b.f);
}
__device__ __forceinline__ void gl_lds16(const void* g, void* l) {
  __builtin_amdgcn_global_load_lds(
      (const __attribute__((address_space(1))) void*)g,
      (__attribute__((address_space(3))) void*)l, 16, 0, 0);
}

#define WAITV8 asm volatile("s_waitcnt vmcnt(8)" ::: "memory")
#define WAITV4 asm volatile("s_waitcnt vmcnt(4)" ::: "memory")
#define WAITV0 asm volatile("s_waitcnt vmcnt(0)" ::: "memory")
#define BAR()  __builtin_amdgcn_s_barrier()

// ---------------- K0: fp32 -> bf16 weight convert ----------------
__global__ __launch_bounds__(256) void wconv(const float* __restrict__ src,
                                             ushortT* __restrict__ dst, int n) {
  int i = (blockIdx.x * 256 + threadIdx.x) * 4;
  if (i < n) {
    float4 v = *(const float4*)(src + i);
    uint2 o;
    o.x = (unsigned)f2bf(v.x) | ((unsigned)f2bf(v.y) << 16);
    o.y = (unsigned)f2bf(v.z) | ((unsigned)f2bf(v.w) << 16);
    *(uint2*)(dst + i) = o;
  }
}

// ---------------- K1: groupnorm stats (one block per (b,g)) ----------------
__global__ __launch_bounds__(256) void gn_stats(const float* __restrict__ x,
                                                float2* __restrict__ stats) {
  int bg = blockIdx.x;
  const float* base = x + (size_t)bg * 65536;
  int tid = threadIdx.x;
  float s = 0.f, s2 = 0.f;
  for (int i = tid; i < 16384; i += 256) {
    float4 v = *(const float4*)(base + (size_t)i * 4);
    s  += v.x + v.y + v.z + v.w;
    s2 += v.x * v.x + v.y * v.y + v.z * v.z + v.w * v.w;
  }
  #pragma unroll
  for (int off = 32; off > 0; off >>= 1) {
    s  += __shfl_down(s, off);
    s2 += __shfl_down(s2, off);
  }
  __shared__ float red[8];
  int w = tid >> 6, l = tid & 63;
  if (l == 0) { red[w] = s; red[w + 4] = s2; }
  __syncthreads();
  if (tid == 0) {
    float ts = red[0] + red[1] + red[2] + red[3];
    float t2 = red[4] + red[5] + red[6] + red[7];
    float mean = ts * (1.f / 65536.f);
    float var  = t2 * (1.f / 65536.f) - mean * mean;
    stats[bg] = make_float2(mean, rsqrtf(var + 1e-5f));
  }
}

// ---------------- K2: normalize + transpose -> h[b*n][c] bf16 ----------------
__global__ __launch_bounds__(512) void norm_tr(const float* __restrict__ x,
                                               const float* __restrict__ nw,
                                               const float* __restrict__ nb,
                                               const float2* __restrict__ stats,
                                               ushortT* __restrict__ h) {
  __shared__ float t[64][65];
  int n0 = blockIdx.x * 64, c0 = blockIdx.y * 64, b = blockIdx.z;
  int tx = threadIdx.x, ty = threadIdx.y;
  #pragma unroll
  for (int j = ty; j < 64; j += 8) {
    int c = c0 + j;
    float2 ms = stats[b * 32 + (c >> 4)];
    float v = x[((size_t)b * 512 + c) * 4096 + n0 + tx];
    t[j][tx] = (v - ms.x) * ms.y * nw[c] + nb[c];
  }
  __syncthreads();
  #pragma unroll
  for (int j = ty; j < 64; j += 8) {
    int n = n0 + j;
    h[((size_t)b * 4096 + n) * 512 + c0 + tx] = f2bf(t[tx][j]);
  }
}

// ================= 256x256 8-wave phase-split GEMM core =================
// K=512, BK=32, 4-deep LDS ring (4 x (A 16KB + B 16KB) = 128KB).
// Stage tile t+3 while computing t: its buffer's last reader finished at
// group (t-1)'s end barrier -> counted vmcnt(8) is race-free by construction.
// LDS XOR swizzle slot^=(row>>1)&3 applied on BOTH sides (pre-swizzled
// global source for global_load_lds; swizzled ds_read addr) -> 2-way only.
__device__ __forceinline__ void core256(const ushortT* __restrict__ A,
                                        const ushortT* __restrict__ Bm,
                                        ushortT* lds, int m0, int n0,
                                        float4v (&acc)[8][4]) {
  const int tid = threadIdx.x;
  const int w = tid >> 6, l = tid & 63;
  const int wm = w >> 2, wn = w & 3;      // 2 M-halves x 4 N-quarters
  // staging: wave w covers tile rows [w*32, w*32+32); 2 loads each for A,B
  const int ra = w * 32 + (l >> 2);
  const int sc = ((l & 3) ^ ((ra >> 1) & 3)) * 8;   // pre-swizzled source slot
  const ushortT* pa = A + (size_t)(m0 + ra) * 512 + sc;
  const ushortT* pb = Bm + (size_t)(n0 + ra) * 512 + sc;
  const int dstoff = w * 1024;            // shorts
  // fragment read offsets (swizzle term identical for all fm/fn: rows step by 16)
  const int swz = ((l >> 4) ^ (((l & 15) >> 1) & 3)) * 8;
  const int baseA = (wm * 128 + (l & 15)) * 32 + swz;
  const int baseB = 8192 + (wn * 64 + (l & 15)) * 32 + swz;

  auto stageA = [&](int t) {
    ushortT* d = lds + (t & 3) * 16384 + dstoff;
    gl_lds16(pa + t * 32, d);
    gl_lds16(pa + t * 32 + 16 * 512, d + 512);
  };
  auto stageB = [&](int t) {
    ushortT* d = lds + (t & 3) * 16384 + 8192 + dstoff;
    gl_lds16(pb + t * 32, d);
    gl_lds16(pb + t * 32 + 16 * 512, d + 512);
  };

  // prologue: tiles 0,1,2 in flight; drain tile 0 (leave 8 = tiles 1,2)
  stageA(0); stageB(0); stageA(1); stageB(1); stageA(2); stageB(2);
  WAITV8; BAR();

  #pragma unroll 1
  for (int t = 0; t < 16; ++t) {
    const ushortT* buf = lds + (t & 3) * 16384;
    // ---- phase A: read A frags + B(0,1), stage A of t+3, MFMA left half ----
    short8v a[8];
    #pragma unroll
    for (int fm = 0; fm < 8; ++fm)
      a[fm] = *(const short8v*)(buf + baseA + fm * 512);
    short8v b0 = *(const short8v*)(buf + baseB);
    short8v b1 = *(const short8v*)(buf + baseB + 512);
    if (t + 3 < 16) stageA(t + 3);
    BAR();
    __builtin_amdgcn_s_setprio(1);
    #pragma unroll
    for (int fm = 0; fm < 8; ++fm) {
      acc[fm][0] = __builtin_amdgcn_mfma_f32_16x16x32_bf16(a[fm], b0, acc[fm][0], 0, 0, 0);
      acc[fm][1] = __builtin_amdgcn_mfma_f32_16x16x32_bf16(a[fm], b1, acc[fm][1], 0, 0, 0);
    }
    __builtin_amdgcn_s_setprio(0);
    BAR();
    // ---- phase B: read B(2,3), stage B of t+3, MFMA right half ----
    short8v b2 = *(const short8v*)(buf + baseB + 1024);
    short8v b3 = *(const short8v*)(buf + baseB + 1536);
    if (t + 3 < 16) stageB(t + 3);
    BAR();
    __builtin_amdgcn_s_setprio(1);
    #pragma unroll
    for (int fm = 0; fm < 8; ++fm) {
      acc[fm][2] = __builtin_amdgcn_mfma_f32_16x16x32_bf16(a[fm], b2, acc[fm][2], 0, 0, 0);
      acc[fm][3] = __builtin_amdgcn_mfma_f32_16x16x32_bf16(a[fm], b3, acc[fm][3], 0, 0, 0);
    }
    __builtin_amdgcn_s_setprio(0);
    // counted drain: tile t+1 must be complete; tiles t+2,t+3 stay in flight
    if (t <= 12)      { WAITV8; }
    else if (t == 13) { WAITV4; }
    else              { WAITV0; }
    BAR();
  }
}

// ---------------- K3: qkv GEMM (65536 x 1536 x 512) -> bf16 ----------------
__global__ __launch_bounds__(512, 2) void gemm_qkv(const ushortT* __restrict__ h,
                                                   const ushortT* __restrict__ wq,
                                                   const float* __restrict__ bias,
                                                   ushortT* __restrict__ outq) {
  __shared__ ushortT lds[65536];   // 128 KB
  int bid = blockIdx.x;
  int wg = (bid & 7) * 192 + (bid >> 3);     // bijective XCD swizzle (1536 % 8 == 0)
  int m0 = (wg / 6) * 256, n0 = (wg % 6) * 256;  // N fastest -> A reused in-XCD-L2
  float4v acc[8][4] = {};
  core256(h, wq, lds, m0, n0, acc);
  const int tid = threadIdx.x;
  const int w = tid >> 6, l = tid & 63;
  const int wm = w >> 2, wn = w & 3;
  __syncthreads();
  // per-wave LDS transpose -> coalesced 32B/lane stores
  ushortT* es = lds + w * 1280;              // 16 x 72 shorts
  float bb[4];
  #pragma unroll
  for (int fn = 0; fn < 4; ++fn) bb[fn] = bias[n0 + wn * 64 + fn * 16 + (l & 15)];
  int r = l >> 2, g = l & 3;
  #pragma unroll
  for (int fm = 0; fm < 8; ++fm) {
    #pragma unroll
    for (int fn = 0; fn < 4; ++fn)
      #pragma unroll
      for (int j = 0; j < 4; ++j)
        es[((l >> 4) * 4 + j) * 72 + fn * 16 + (l & 15)] = f2bf(acc[fm][fn][j] + bb[fn]);
    uint4 v0 = *(const uint4*)(es + r * 72 + g * 16);
    uint4 v1 = *(const uint4*)(es + r * 72 + g * 16 + 8);
    size_t mrow = (size_t)m0 + wm * 128 + fm * 16 + r;
    uint4* dst = (uint4*)(outq + mrow * 1536 + n0 + wn * 64 + g * 16);
    dst[0] = v0; dst[1] = v1;
  }
}

// ---------------- K4: per-position 8x8 head attention (LDS-free) ----------
// one thread per (position, head); 8 lanes share a position -> K/V reads
// are wave-level broadcast (16B x 8 unique per instruction).
__global__ __launch_bounds__(256) void attn_k(const ushortT* __restrict__ qkv,
                                              ushortT* __restrict__ o) {
  int gp = blockIdx.x * 256 + threadIdx.x;
  int pos = gp >> 3, hh = gp & 7;
  const ushortT* base = qkv + (size_t)pos * 1536;
  float q[64];
  #pragma unroll
  for (int i = 0; i < 8; ++i) {
    uint4 u = *(const uint4*)(base + hh * 64 + i * 8);
    float2 t0 = up2(u.x), t1 = up2(u.y), t2 = up2(u.z), t3 = up2(u.w);
    q[i*8+0]=t0.x; q[i*8+1]=t0.y; q[i*8+2]=t1.x; q[i*8+3]=t1.y;
    q[i*8+4]=t2.x; q[i*8+5]=t2.y; q[i*8+6]=t3.x; q[i*8+7]=t3.y;
  }
  float lg[8];
  #pragma unroll
  for (int g = 0; g < 8; ++g) {
    float s = 0.f;
    #pragma unroll
    for (int d8 = 0; d8 < 8; ++d8) {
      uint4 kk = *(const uint4*)(base + 512 + g * 64 + d8 * 8);
      float2 k0 = up2(kk.x), k1 = up2(kk.y), k2 = up2(kk.z), k3 = up2(kk.w);
      s += q[d8*8+0]*k0.x + q[d8*8+1]*k0.y + q[d8*8+2]*k1.x + q[d8*8+3]*k1.y
         + q[d8*8+4]*k2.x + q[d8*8+5]*k2.y + q[d8*8+6]*k3.x + q[d8*8+7]*k3.y;
    }
    lg[g] = s * 0.125f;
  }
  float mx = lg[0];
  #pragma unroll
  for (int g = 1; g < 8; ++g) mx = fmaxf(mx, lg[g]);
  float ssum = 0.f;
  #pragma unroll
  for (int g = 0; g < 8; ++g) { lg[g] = __expf(lg[g] - mx); ssum += lg[g]; }
  float inv = 1.f / ssum;
  #pragma unroll
  for (int g = 0; g < 8; ++g) lg[g] *= inv;
  float oa[64];
  #pragma unroll
  for (int i = 0; i < 64; ++i) oa[i] = 0.f;
  #pragma unroll
  for (int g = 0; g < 8; ++g) {
    float wg = lg[g];
    #pragma unroll
    for (int d8 = 0; d8 < 8; ++d8) {
      uint4 vv = *(const uint4*)(base + 1024 + g * 64 + d8 * 8);
      float2 v0 = up2(vv.x), v1 = up2(vv.y), v2 = up2(vv.z), v3 = up2(vv.w);
      oa[d8*8+0] += wg*v0.x; oa[d8*8+1] += wg*v0.y;
      oa[d8*8+2] += wg*v1.x; oa[d8*8+3] += wg*v1.y;
      oa[d8*8+4] += wg*v2.x; oa[d8*8+5] += wg*v2.y;
      oa[d8*8+6] += wg*v3.x; oa[d8*8+7] += wg*v3.y;
    }
  }
  ushortT* dst = o + (size_t)pos * 512 + hh * 64;
  #pragma unroll
  for (int i = 0; i < 8; ++i) {
    uint4 w_;
    w_.x = (unsigned)f2bf(oa[i*8+0]) | ((unsigned)f2bf(oa[i*8+1]) << 16);
    w_.y = (unsigned)f2bf(oa[i*8+2]) | ((unsigned)f2bf(oa[i*8+3]) << 16);
    w_.z = (unsigned)f2bf(oa[i*8+4]) | ((unsigned)f2bf(oa[i*8+5]) << 16);
    w_.w = (unsigned)f2bf(oa[i*8+6]) | ((unsigned)f2bf(oa[i*8+7]) << 16);
    *(uint4*)(dst + i * 8) = w_;
  }
}

// ---------------- K5: proj GEMM + residual + transposed fp32 write ---------
__global__ __launch_bounds__(512, 2) void gemm_proj(const ushortT* __restrict__ o,
                                                    const ushortT* __restrict__ wp,
                                                    const float* __restrict__ bias,
                                                    const float* __restrict__ x,
                                                    float* __restrict__ out) {
  __shared__ ushortT lds[65536];
  int bid = blockIdx.x;
  int wg = (bid & 7) * 64 + (bid >> 3);      // bijective XCD swizzle (512 % 8 == 0)
  int m0 = (wg >> 1) * 256, n0 = (wg & 1) * 256;
  float4v acc[8][4] = {};
  core256(o, wp, lds, m0, n0, acc);
  const int tid = threadIdx.x;
  const int w = tid >> 6, l = tid & 63;
  const int wm = w >> 2, wn = w & 3;
  __syncthreads();
  // per-wave fp32 transpose: each lane owns one channel, writes 64B rows
  float* es = (float*)((char*)lds + w * 4608);   // 16 x 68 floats
  int b = m0 >> 12;                               // 256-row tile never straddles batch
  int c = n0 + wn * 64 + l;
  float bc = bias[c];
  const float* xrow = x + ((size_t)b * 512 + c) * 4096;
  float* orow = out + ((size_t)b * 512 + c) * 4096;
  int nb0 = (m0 & 4095) + wm * 128;
  #pragma unroll
  for (int fm = 0; fm < 8; ++fm) {
    #pragma unroll
    for (int fn = 0; fn < 4; ++fn)
      #pragma unroll
      for (int j = 0; j < 4; ++j)
        es[((l >> 4) * 4 + j) * 68 + fn * 16 + (l & 15)] = acc[fm][fn][j];
    int nb = nb0 + fm * 16;
    #pragma unroll
    for (int q4 = 0; q4 < 4; ++q4) {
      float4 xv = *(const float4*)(xrow + nb + q4 * 4);
      float4 ov;
      ov.x = xv.x + bc + es[(q4 * 4 + 0) * 68 + l];
      ov.y = xv.y + bc + es[(q4 * 4 + 1) * 68 + l];
      ov.z = xv.z + bc + es[(q4 * 4 + 2) * 68 + l];
      ov.w = xv.w + bc + es[(q4 * 4 + 3) * 68 + l];
      *(float4*)(orow + nb + q4 * 4) = ov;
    }
  }
}

// ---------------- launcher ----------------
extern "C" void kernel_launch(void* const* d_in, const int* in_sizes, int n_in,
                              void* d_out, int out_size, void* d_ws, size_t ws_size,
                              hipStream_t stream) {
  const float* x     = (const float*)d_in[0];
  const float* nw    = (const float*)d_in[1];
  const float* nb    = (const float*)d_in[2];
  const float* qkvw  = (const float*)d_in[3];
  const float* qkvb  = (const float*)d_in[4];
  const float* pw    = (const float*)d_in[5];
  const float* pb    = (const float*)d_in[6];
  float* out = (float*)d_out;
  char* ws = (char*)d_ws;

  const size_t OFF_WQ   = 4096;                       // stats: 512 * float2
  const size_t OFF_WP   = OFF_WQ + 1572864;           // qkv_w bf16
  const size_t OFF_H    = OFF_WP + 524288;            // proj_w bf16
  const size_t OFF_QKV  = OFF_H + 67108864;           // h / attn-out (aliased)

  float2* stats   = (float2*)ws;
  ushortT* wq_b   = (ushortT*)(ws + OFF_WQ);
  ushortT* wp_b   = (ushortT*)(ws + OFF_WP);
  ushortT* h      = (ushortT*)(ws + OFF_H);
  ushortT* qkv    = (ushortT*)(ws + OFF_QKV);

  wconv<<<768, 256, 0, stream>>>(qkvw, wq_b, 786432);
  wconv<<<256, 256, 0, stream>>>(pw,   wp_b, 262144);
  gn_stats<<<512, 256, 0, stream>>>(x, stats);
  norm_tr<<<dim3(64, 8, 16), dim3(64, 8), 0, stream>>>(x, nw, nb, stats, h);
  gemm_qkv<<<1536, 512, 0, stream>>>(h, wq_b, qkvb, qkv);
  attn_k<<<2048, 256, 0, stream>>>(qkv, h);
  gemm_proj<<<512, 512, 0, stream>>>(h, wp_b, pb, x, out);
}

// Round 3
// 409.247 us; speedup vs baseline: 1.1615x; 1.0458x over previous
//
#include <hip/hip_runtime.h>

// ---------------- types / helpers ----------------
typedef __attribute__((ext_vector_type(8))) short short8v;   // 8 bf16 (4 VGPR)
typedef __attribute__((ext_vector_type(4))) float float4v;   // MFMA acc
typedef unsigned short ushortT;

__device__ __forceinline__ unsigned short f2bf(float f) {
  union { float f; unsigned u; } a; a.f = f;
  unsigned r = a.u + 0x7fffu + ((a.u >> 16) & 1u);   // RNE
  return (unsigned short)(r >> 16);
}
__device__ __forceinline__ float2 up2(unsigned u) {  // packed 2xbf16 -> 2 floats
  union { unsigned u; float f; } a, b;
  a.u = u << 16; b.u = u & 0xffff0000u;
  return make_float2(a.f, b.f);
}
__device__ __forceinline__ void gl_lds16(const void* g, void* l) {
  __builtin_amdgcn_global_load_lds(
      (const __attribute__((address_space(1))) void*)g,
      (__attribute__((address_space(3))) void*)l, 16, 0, 0);
}

#define WAITV4 asm volatile("s_waitcnt vmcnt(4)" ::: "memory")
#define WAITV0 asm volatile("s_waitcnt vmcnt(0)" ::: "memory")
#define BAR()  __builtin_amdgcn_s_barrier()
#define MFMA16(d, a, b) d = __builtin_amdgcn_mfma_f32_16x16x32_bf16(a, b, d, 0, 0, 0)

// ---------------- K0: fp32 -> bf16 weight convert ----------------
__global__ __launch_bounds__(256) void wconv(const float* __restrict__ src,
                                             ushortT* __restrict__ dst, int n) {
  int i = (blockIdx.x * 256 + threadIdx.x) * 4;
  if (i < n) {
    float4 v = *(const float4*)(src + i);
    uint2 o;
    o.x = (unsigned)f2bf(v.x) | ((unsigned)f2bf(v.y) << 16);
    o.y = (unsigned)f2bf(v.z) | ((unsigned)f2bf(v.w) << 16);
    *(uint2*)(dst + i) = o;
  }
}

// ---------------- K1: groupnorm stats (one block per (b,g)) ----------------
__global__ __launch_bounds__(256) void gn_stats(const float* __restrict__ x,
                                                float2* __restrict__ stats) {
  int bg = blockIdx.x;
  const float* base = x + (size_t)bg * 65536;
  int tid = threadIdx.x;
  float s = 0.f, s2 = 0.f;
  for (int i = tid; i < 16384; i += 256) {
    float4 v = *(const float4*)(base + (size_t)i * 4);
    s  += v.x + v.y + v.z + v.w;
    s2 += v.x * v.x + v.y * v.y + v.z * v.z + v.w * v.w;
  }
  #pragma unroll
  for (int off = 32; off > 0; off >>= 1) {
    s  += __shfl_down(s, off);
    s2 += __shfl_down(s2, off);
  }
  __shared__ float red[8];
  int w = tid >> 6, l = tid & 63;
  if (l == 0) { red[w] = s; red[w + 4] = s2; }
  __syncthreads();
  if (tid == 0) {
    float ts = red[0] + red[1] + red[2] + red[3];
    float t2 = red[4] + red[5] + red[6] + red[7];
    float mean = ts * (1.f / 65536.f);
    float var  = t2 * (1.f / 65536.f) - mean * mean;
    stats[bg] = make_float2(mean, rsqrtf(var + 1e-5f));
  }
}

// ---------------- K2: normalize + transpose -> h[b*n][c] bf16 ----------------
__global__ __launch_bounds__(512) void norm_tr(const float* __restrict__ x,
                                               const float* __restrict__ nw,
                                               const float* __restrict__ nb,
                                               const float2* __restrict__ stats,
                                               ushortT* __restrict__ h) {
  __shared__ float t[64][65];
  int n0 = blockIdx.x * 64, c0 = blockIdx.y * 64, b = blockIdx.z;
  int tx = threadIdx.x, ty = threadIdx.y;
  #pragma unroll
  for (int j = ty; j < 64; j += 8) {
    int c = c0 + j;
    float2 ms = stats[b * 32 + (c >> 4)];
    float v = x[((size_t)b * 512 + c) * 4096 + n0 + tx];
    t[j][tx] = (v - ms.x) * ms.y * nw[c] + nb[c];
  }
  __syncthreads();
  #pragma unroll
  for (int j = ty; j < 64; j += 8) {
    int n = n0 + j;
    h[((size_t)b * 4096 + n) * 512 + c0 + tx] = f2bf(t[tx][j]);
  }
}

// ================= 256x256 8-wave pipelined GEMM core =================
// K=512, BK=32, 4-deep LDS ring (128KB). Fragment ds_reads issued ONE PHASE
// AHEAD (6 reads/phase balanced) so the lgkmcnt drain of a cluster's operands
// hides under the PREVIOUS cluster's MFMAs. End-of-tile vmcnt(4): buf t+2
// staged before tile t+1's read-ahead touches it (FIFO: outstanding at end of
// t = stages t+2,t+3 = 8 ops -> drain to 4 retires t+2).
__device__ __forceinline__ void core256(const ushortT* __restrict__ A,
                                        const ushortT* __restrict__ Bm,
                                        ushortT* lds, int m0, int n0,
                                        float4v (&acc)[8][4]) {
  const int tid = threadIdx.x;
  const int w = tid >> 6, l = tid & 63;
  const int wm = w >> 2, wn = w & 3;      // 2 M-halves x 4 N-quarters
  const int ra = w * 32 + (l >> 2);
  const int sc = ((l & 3) ^ ((ra >> 1) & 3)) * 8;   // pre-swizzled source slot
  const ushortT* pa = A + (size_t)(m0 + ra) * 512 + sc;
  const ushortT* pb = Bm + (size_t)(n0 + ra) * 512 + sc;
  const int dstoff = w * 1024;            // shorts
  const int swz = ((l >> 4) ^ (((l & 15) >> 1) & 3)) * 8;
  const int baseA = (wm * 128 + (l & 15)) * 32 + swz;
  const int baseB = 8192 + (wn * 64 + (l & 15)) * 32 + swz;

  auto stageA = [&](int t) {
    ushortT* d = lds + (t & 3) * 16384 + dstoff;
    gl_lds16(pa + t * 32, d);
    gl_lds16(pa + t * 32 + 16 * 512, d + 512);
  };
  auto stageB = [&](int t) {
    ushortT* d = lds + (t & 3) * 16384 + 8192 + dstoff;
    gl_lds16(pb + t * 32, d);
    gl_lds16(pb + t * 32 + 16 * 512, d + 512);
  };

  short8v aX[8], aY[8], b0X, b1X, b0Y, b1Y, bB0, bB1;

  // prologue: stage tiles 0,1,2; ensure 0,1 resident; preload tile-0 frags
  stageA(0); stageB(0); stageA(1); stageB(1); stageA(2); stageB(2);
  WAITV4; BAR();
  #pragma unroll
  for (int i = 0; i < 8; ++i) aX[i] = *(const short8v*)(lds + baseA + i * 512);
  b0X = *(const short8v*)(lds + baseB);
  b1X = *(const short8v*)(lds + baseB + 512);

  auto tile = [&](int t, short8v (&ac)[8], short8v (&an)[8],
                  short8v& b0c, short8v& b1c, short8v& b0n, short8v& b1n) {
    const ushortT* buf  = lds + (t & 3) * 16384;
    const ushortT* bufN = lds + ((t + 1) & 3) * 16384;
    // ---- phase A: read b23(t) + aNext[0..3]; stage A(t+3); cluster left ----
    bB0 = *(const short8v*)(buf + baseB + 1024);
    bB1 = *(const short8v*)(buf + baseB + 1536);
    if (t < 15) {
      #pragma unroll
      for (int i = 0; i < 4; ++i) an[i] = *(const short8v*)(bufN + baseA + i * 512);
    }
    if (t + 3 < 16) stageA(t + 3);
    BAR();
    __builtin_amdgcn_s_setprio(1);
    #pragma unroll
    for (int fm = 0; fm < 8; ++fm) {
      MFMA16(acc[fm][0], ac[fm], b0c);
      MFMA16(acc[fm][1], ac[fm], b1c);
    }
    __builtin_amdgcn_s_setprio(0);
    BAR();
    // ---- phase B: read aNext[4..7] + b01(t+1); stage B(t+3); cluster right --
    if (t < 15) {
      #pragma unroll
      for (int i = 4; i < 8; ++i) an[i] = *(const short8v*)(bufN + baseA + i * 512);
      b0n = *(const short8v*)(bufN + baseB);
      b1n = *(const short8v*)(bufN + baseB + 512);
    }
    if (t + 3 < 16) stageB(t + 3);
    BAR();
    __builtin_amdgcn_s_setprio(1);
    #pragma unroll
    for (int fm = 0; fm < 8; ++fm) {
      MFMA16(acc[fm][2], ac[fm], bB0);
      MFMA16(acc[fm][3], ac[fm], bB1);
    }
    __builtin_amdgcn_s_setprio(0);
    if (t <= 12)      { WAITV4; }
    else if (t == 13) { WAITV0; }
    BAR();
  };

  #pragma unroll 1
  for (int tt = 0; tt < 16; tt += 2) {
    tile(tt,     aX, aY, b0X, b1X, b0Y, b1Y);
    tile(tt + 1, aY, aX, b0Y, b1Y, b0X, b1X);
  }
}

// ---------------- K3: qkv GEMM (65536 x 1536 x 512) -> bf16 ----------------
__global__ __launch_bounds__(512, 2) void gemm_qkv(const ushortT* __restrict__ h,
                                                   const ushortT* __restrict__ wq,
                                                   const float* __restrict__ bias,
                                                   ushortT* __restrict__ outq) {
  __shared__ ushortT lds[65536];   // 128 KB
  int bid = blockIdx.x;
  int wg = (bid & 7) * 192 + (bid >> 3);     // bijective XCD swizzle (1536 % 8 == 0)
  int m0 = (wg / 6) * 256, n0 = (wg % 6) * 256;  // N fastest -> A reused in-XCD-L2
  float4v acc[8][4] = {};
  core256(h, wq, lds, m0, n0, acc);
  const int tid = threadIdx.x;
  const int w = tid >> 6, l = tid & 63;
  const int wm = w >> 2, wn = w & 3;
  __syncthreads();
  // per-wave LDS transpose -> coalesced 32B/lane stores
  ushortT* es = lds + w * 1280;              // 16 x 72 shorts
  float bb[4];
  #pragma unroll
  for (int fn = 0; fn < 4; ++fn) bb[fn] = bias[n0 + wn * 64 + fn * 16 + (l & 15)];
  int r = l >> 2, g = l & 3;
  #pragma unroll
  for (int fm = 0; fm < 8; ++fm) {
    #pragma unroll
    for (int fn = 0; fn < 4; ++fn)
      #pragma unroll
      for (int j = 0; j < 4; ++j)
        es[((l >> 4) * 4 + j) * 72 + fn * 16 + (l & 15)] = f2bf(acc[fm][fn][j] + bb[fn]);
    uint4 v0 = *(const uint4*)(es + r * 72 + g * 16);
    uint4 v1 = *(const uint4*)(es + r * 72 + g * 16 + 8);
    size_t mrow = (size_t)m0 + wm * 128 + fm * 16 + r;
    uint4* dst = (uint4*)(outq + mrow * 1536 + n0 + wn * 64 + g * 16);
    dst[0] = v0; dst[1] = v1;
  }
}

// ---------------- K4: per-position 8x8 head attention (LDS-free) ----------
__global__ __launch_bounds__(256) void attn_k(const ushortT* __restrict__ qkv,
                                              ushortT* __restrict__ o) {
  int gp = blockIdx.x * 256 + threadIdx.x;
  int pos = gp >> 3, hh = gp & 7;
  const ushortT* base = qkv + (size_t)pos * 1536;
  float q[64];
  #pragma unroll
  for (int i = 0; i < 8; ++i) {
    uint4 u = *(const uint4*)(base + hh * 64 + i * 8);
    float2 t0 = up2(u.x), t1 = up2(u.y), t2 = up2(u.z), t3 = up2(u.w);
    q[i*8+0]=t0.x; q[i*8+1]=t0.y; q[i*8+2]=t1.x; q[i*8+3]=t1.y;
    q[i*8+4]=t2.x; q[i*8+5]=t2.y; q[i*8+6]=t3.x; q[i*8+7]=t3.y;
  }
  float lg[8];
  #pragma unroll
  for (int g = 0; g < 8; ++g) {
    float s = 0.f;
    #pragma unroll
    for (int d8 = 0; d8 < 8; ++d8) {
      uint4 kk = *(const uint4*)(base + 512 + g * 64 + d8 * 8);
      float2 k0 = up2(kk.x), k1 = up2(kk.y), k2 = up2(kk.z), k3 = up2(kk.w);
      s += q[d8*8+0]*k0.x + q[d8*8+1]*k0.y + q[d8*8+2]*k1.x + q[d8*8+3]*k1.y
         + q[d8*8+4]*k2.x + q[d8*8+5]*k2.y + q[d8*8+6]*k3.x + q[d8*8+7]*k3.y;
    }
    lg[g] = s * 0.125f;
  }
  float mx = lg[0];
  #pragma unroll
  for (int g = 1; g < 8; ++g) mx = fmaxf(mx, lg[g]);
  float ssum = 0.f;
  #pragma unroll
  for (int g = 0; g < 8; ++g) { lg[g] = __expf(lg[g] - mx); ssum += lg[g]; }
  float inv = 1.f / ssum;
  #pragma unroll
  for (int g = 0; g < 8; ++g) lg[g] *= inv;
  float oa[64];
  #pragma unroll
  for (int i = 0; i < 64; ++i) oa[i] = 0.f;
  #pragma unroll
  for (int g = 0; g < 8; ++g) {
    float wg = lg[g];
    #pragma unroll
    for (int d8 = 0; d8 < 8; ++d8) {
      uint4 vv = *(const uint4*)(base + 1024 + g * 64 + d8 * 8);
      float2 v0 = up2(vv.x), v1 = up2(vv.y), v2 = up2(vv.z), v3 = up2(vv.w);
      oa[d8*8+0] += wg*v0.x; oa[d8*8+1] += wg*v0.y;
      oa[d8*8+2] += wg*v1.x; oa[d8*8+3] += wg*v1.y;
      oa[d8*8+4] += wg*v2.x; oa[d8*8+5] += wg*v2.y;
      oa[d8*8+6] += wg*v3.x; oa[d8*8+7] += wg*v3.y;
    }
  }
  ushortT* dst = o + (size_t)pos * 512 + hh * 64;
  #pragma unroll
  for (int i = 0; i < 8; ++i) {
    uint4 w_;
    w_.x = (unsigned)f2bf(oa[i*8+0]) | ((unsigned)f2bf(oa[i*8+1]) << 16);
    w_.y = (unsigned)f2bf(oa[i*8+2]) | ((unsigned)f2bf(oa[i*8+3]) << 16);
    w_.z = (unsigned)f2bf(oa[i*8+4]) | ((unsigned)f2bf(oa[i*8+5]) << 16);
    w_.w = (unsigned)f2bf(oa[i*8+6]) | ((unsigned)f2bf(oa[i*8+7]) << 16);
    *(uint4*)(dst + i * 8) = w_;
  }
}

// ---------------- K5: proj GEMM + residual + transposed fp32 write ---------
__global__ __launch_bounds__(512, 2) void gemm_proj(const ushortT* __restrict__ o,
                                                    const ushortT* __restrict__ wp,
                                                    const float* __restrict__ bias,
                                                    const float* __restrict__ x,
                                                    float* __restrict__ out) {
  __shared__ ushortT lds[65536];
  int bid = blockIdx.x;
  int wg = (bid & 7) * 64 + (bid >> 3);      // bijective XCD swizzle (512 % 8 == 0)
  int m0 = (wg >> 1) * 256, n0 = (wg & 1) * 256;
  float4v acc[8][4] = {};
  core256(o, wp, lds, m0, n0, acc);
  const int tid = threadIdx.x;
  const int w = tid >> 6, l = tid & 63;
  const int wm = w >> 2, wn = w & 3;
  __syncthreads();
  float* es = (float*)((char*)lds + w * 4608);   // 16 x 68 floats per wave
  int b = m0 >> 12;
  int c = n0 + wn * 64 + l;
  float bc = bias[c];
  const float* xrow = x + ((size_t)b * 512 + c) * 4096;
  float* orow = out + ((size_t)b * 512 + c) * 4096;
  int nb0 = (m0 & 4095) + wm * 128;
  #pragma unroll
  for (int fm = 0; fm < 8; ++fm) {
    #pragma unroll
    for (int fn = 0; fn < 4; ++fn)
      #pragma unroll
      for (int j = 0; j < 4; ++j)
        es[((l >> 4) * 4 + j) * 68 + fn * 16 + (l & 15)] = acc[fm][fn][j];
    int nb = nb0 + fm * 16;
    #pragma unroll
    for (int q4 = 0; q4 < 4; ++q4) {
      float4 xv = *(const float4*)(xrow + nb + q4 * 4);
      float4 ov;
      ov.x = xv.x + bc + es[(q4 * 4 + 0) * 68 + l];
      ov.y = xv.y + bc + es[(q4 * 4 + 1) * 68 + l];
      ov.z = xv.z + bc + es[(q4 * 4 + 2) * 68 + l];
      ov.w = xv.w + bc + es[(q4 * 4 + 3) * 68 + l];
      *(float4*)(orow + nb + q4 * 4) = ov;
    }
  }
}

// ---------------- launcher ----------------
extern "C" void kernel_launch(void* const* d_in, const int* in_sizes, int n_in,
                              void* d_out, int out_size, void* d_ws, size_t ws_size,
                              hipStream_t stream) {
  const float* x     = (const float*)d_in[0];
  const float* nw    = (const float*)d_in[1];
  const float* nb    = (const float*)d_in[2];
  const float* qkvw  = (const float*)d_in[3];
  const float* qkvb  = (const float*)d_in[4];
  const float* pw    = (const float*)d_in[5];
  const float* pb    = (const float*)d_in[6];
  float* out = (float*)d_out;
  char* ws = (char*)d_ws;

  const size_t OFF_WQ   = 4096;
  const size_t OFF_WP   = OFF_WQ + 1572864;
  const size_t OFF_H    = OFF_WP + 524288;
  const size_t OFF_QKV  = OFF_H + 67108864;

  float2* stats   = (float2*)ws;
  ushortT* wq_b   = (ushortT*)(ws + OFF_WQ);
  ushortT* wp_b   = (ushortT*)(ws + OFF_WP);
  ushortT* h      = (ushortT*)(ws + OFF_H);
  ushortT* qkv    = (ushortT*)(ws + OFF_QKV);

  wconv<<<768, 256, 0, stream>>>(qkvw, wq_b, 786432);
  wconv<<<256, 256, 0, stream>>>(pw,   wp_b, 262144);
  gn_stats<<<512, 256, 0, stream>>>(x, stats);
  norm_tr<<<dim3(64, 8, 16), dim3(64, 8), 0, stream>>>(x, nw, nb, stats, h);
  gemm_qkv<<<1536, 512, 0, stream>>>(h, wq_b, qkvb, qkv);
  attn_k<<<2048, 256, 0, stream>>>(qkv, h);
  gemm_proj<<<512, 512, 0, stream>>>(h, wp_b, pb, x, out);
}

// Round 4
// 406.686 us; speedup vs baseline: 1.1688x; 1.0063x over previous
//
#include <hip/hip_runtime.h>

// ---------------- types / helpers ----------------
typedef __attribute__((ext_vector_type(8))) short short8v;   // 8 bf16 (4 VGPR)
typedef __attribute__((ext_vector_type(4))) float float4v;   // MFMA acc
typedef unsigned short ushortT;

__device__ __forceinline__ unsigned short f2bf(float f) {
  union { float f; unsigned u; } a; a.f = f;
  unsigned r = a.u + 0x7fffu + ((a.u >> 16) & 1u);   // RNE
  return (unsigned short)(r >> 16);
}
__device__ __forceinline__ float2 up2(unsigned u) {  // packed 2xbf16 -> 2 floats
  union { unsigned u; float f; } a, b;
  a.u = u << 16; b.u = u & 0xffff0000u;
  return make_float2(a.f, b.f);
}
__device__ __forceinline__ void gl_lds16(const void* g, void* l) {
  __builtin_amdgcn_global_load_lds(
      (const __attribute__((address_space(1))) void*)g,
      (__attribute__((address_space(3))) void*)l, 16, 0, 0);
}

#define WAITV4 asm volatile("s_waitcnt vmcnt(4)" ::: "memory")
#define WAITV0 asm volatile("s_waitcnt vmcnt(0)" ::: "memory")
#define LGKM0  asm volatile("s_waitcnt lgkmcnt(0)" ::: "memory")
#define BAR()  __builtin_amdgcn_s_barrier()
#define MFMA16(d, a, b) d = __builtin_amdgcn_mfma_f32_16x16x32_bf16(a, b, d, 0, 0, 0)

// ---------------- K0: fp32 -> bf16 weight convert ----------------
__global__ __launch_bounds__(256) void wconv(const float* __restrict__ src,
                                             ushortT* __restrict__ dst, int n) {
  int i = (blockIdx.x * 256 + threadIdx.x) * 4;
  if (i < n) {
    float4 v = *(const float4*)(src + i);
    uint2 o;
    o.x = (unsigned)f2bf(v.x) | ((unsigned)f2bf(v.y) << 16);
    o.y = (unsigned)f2bf(v.z) | ((unsigned)f2bf(v.w) << 16);
    *(uint2*)(dst + i) = o;
  }
}

// ---------------- K1: groupnorm stats (one block per (b,g)) ----------------
__global__ __launch_bounds__(256) void gn_stats(const float* __restrict__ x,
                                                float2* __restrict__ stats) {
  int bg = blockIdx.x;
  const float* base = x + (size_t)bg * 65536;
  int tid = threadIdx.x;
  float s = 0.f, s2 = 0.f;
  for (int i = tid; i < 16384; i += 256) {
    float4 v = *(const float4*)(base + (size_t)i * 4);
    s  += v.x + v.y + v.z + v.w;
    s2 += v.x * v.x + v.y * v.y + v.z * v.z + v.w * v.w;
  }
  #pragma unroll
  for (int off = 32; off > 0; off >>= 1) {
    s  += __shfl_down(s, off);
    s2 += __shfl_down(s2, off);
  }
  __shared__ float red[8];
  int w = tid >> 6, l = tid & 63;
  if (l == 0) { red[w] = s; red[w + 4] = s2; }
  __syncthreads();
  if (tid == 0) {
    float ts = red[0] + red[1] + red[2] + red[3];
    float t2 = red[4] + red[5] + red[6] + red[7];
    float mean = ts * (1.f / 65536.f);
    float var  = t2 * (1.f / 65536.f) - mean * mean;
    stats[bg] = make_float2(mean, rsqrtf(var + 1e-5f));
  }
}

// ---------------- K2: normalize + transpose -> h[b*n][c] bf16 ----------------
__global__ __launch_bounds__(512) void norm_tr(const float* __restrict__ x,
                                               const float* __restrict__ nw,
                                               const float* __restrict__ nb,
                                               const float2* __restrict__ stats,
                                               ushortT* __restrict__ h) {
  __shared__ float t[64][65];
  int n0 = blockIdx.x * 64, c0 = blockIdx.y * 64, b = blockIdx.z;
  int tx = threadIdx.x, ty = threadIdx.y;
  #pragma unroll
  for (int j = ty; j < 64; j += 8) {
    int c = c0 + j;
    float2 ms = stats[b * 32 + (c >> 4)];
    float v = x[((size_t)b * 512 + c) * 4096 + n0 + tx];
    t[j][tx] = (v - ms.x) * ms.y * nw[c] + nb[c];
  }
  __syncthreads();
  #pragma unroll
  for (int j = ty; j < 64; j += 8) {
    int n = n0 + j;
    h[((size_t)b * 4096 + n) * 512 + c0 + tx] = f2bf(t[tx][j]);
  }
}

// ================= 256x256 8-wave 8-phase GEMM core (m201 port) ============
// K=512, BK=64, 2 LDS buffers of 64KB (A[256][64] + B[256][64] bf16 each).
// Per K-tile: 4 phases = 4 C-quadrants x K=64. Reads in-phase, before the
// mid barrier; lgkmcnt(0)+fence after it; 16-MFMA cluster in setprio(1).
// One 16KB half-tile staged per phase into a region whose last reader
// finished a phase ago: P1->(t+1).A-bot, P2->(t+1).B-bot, P3->(t+2).B-top,
// P4->(t+2).A-top. vmcnt(4) once per tile at P4 retires all of tile t+1
// (FIFO), leaves t+2's 4 loads in flight (never drains to 0 mid-loop).
// LDS swizzle (G4, 128-B rows): byte ^= (row&7)<<4, applied BOTH sides:
// pre-swizzled global source for gl_lds + swizzled ds_read col.
__device__ __forceinline__ void core256(const ushortT* __restrict__ A,
                                        const ushortT* __restrict__ Bm,
                                        ushortT* lds, int m0, int n0,
                                        float4v (&acc)[8][4]) {
  char* ldsb = (char*)lds;
  const int tid = threadIdx.x;
  const int w = tid >> 6, l = tid & 63;
  const int wm = w >> 2, wn = w & 3;          // 2 M-halves x 4 N-quarters

  // ---- staging (thread-constant parts) ----
  const int P0b = tid * 16, P1b = 8192 + tid * 16;      // byte off within half
  const int r0 = P0b >> 7, r1 = P1b >> 7;               // row within half
  const int s0 = (P0b & 127) ^ ((r0 & 7) << 4);         // swizzled src col
  const int s1 = (P1b & 127) ^ ((r1 & 7) << 4);
  const size_t g0 = (size_t)r0 * 512 + (s0 >> 1);
  const size_t g1 = (size_t)r1 * 512 + (s1 >> 1);
  auto stage = [&](const ushortT* mat, int rowbase, int kt, int bufb, int region) {
    const ushortT* gsrc = mat + (size_t)rowbase * 512 + kt * 64;
    char* dbase = ldsb + bufb + region;
    gl_lds16(gsrc + g0, dbase + P0b);
    gl_lds16(gsrc + g1, dbase + P1b);
  };

  // ---- fragment read offsets ----
  const int colb = (l >> 4) * 16;                       // byte col base
  const int cs0 = colb ^ ((l & 7) << 4);                // ks=0
  const int cs1 = (64 + colb) ^ ((l & 7) << 4);         // ks=1
  const int arow = wm * 16384 + (l & 15) * 128;
  const int brow = 32768 + wn * 8192 + (l & 15) * 128;

  short8v Af[4][2], Bf[4][2];
  auto rdA = [&](int bb, int m, int mhalf) {
    const char* p = ldsb + bb + arow + m * 2048;
    Af[m][0] = *(const short8v*)(p + cs0);
    Af[m][1] = *(const short8v*)(p + cs1);
    (void)mhalf;
  };
  auto rdB = [&](int bb, int n) {
    const char* p = ldsb + bb + brow + n * 2048;
    Bf[n][0] = *(const short8v*)(p + cs0);
    Bf[n][1] = *(const short8v*)(p + cs1);
  };

  #define CLUSTER(MH, NP)                                              \
    { __builtin_amdgcn_s_setprio(1);                                   \
      _Pragma("unroll")                                                \
      for (int mm = 0; mm < 4; ++mm) {                                 \
        _Pragma("unroll")                                              \
        for (int nn = 0; nn < 2; ++nn) {                               \
          MFMA16(acc[(MH)*4+mm][(NP)*2+nn], Af[mm][0], Bf[(NP)*2+nn][0]); \
          MFMA16(acc[(MH)*4+mm][(NP)*2+nn], Af[mm][1], Bf[(NP)*2+nn][1]); \
        } }                                                            \
      __builtin_amdgcn_s_setprio(0); }

  auto tile = [&](int bb, int t1, int t2, bool s1g, bool s2g, int vw) {
    // ---- P1: read A m0-3 + B n0-1 (12); stage (t+1).A-bot ----
    rdA(bb, 0, 0); rdA(bb, 1, 0); rdA(bb, 2, 0); rdA(bb, 3, 0);
    rdB(bb, 0); rdB(bb, 1);
    if (s1g) stage(A, m0 + 128, t1, bb ^ 65536, 16384);
    BAR(); LGKM0;
    CLUSTER(0, 0);
    BAR();
    // ---- P2: read B n2-3 (4); stage (t+1).B-bot ----
    rdB(bb, 2); rdB(bb, 3);
    if (s1g) stage(Bm, n0 + 128, t1, bb ^ 65536, 49152);
    BAR(); LGKM0;
    CLUSTER(0, 1);
    BAR();
    // ---- P3: read A m4-7 (8); stage (t+2).B-top ----
    rdA(bb, 0, 1); rdA(bb, 1, 1); rdA(bb, 2, 1); rdA(bb, 3, 1);
    if (s2g) stage(Bm, n0, t2, bb, 32768);
    BAR(); LGKM0;
    CLUSTER(1, 1);
    BAR();
    // ---- P4: no reads; stage (t+2).A-top; per-tile counted vmcnt ----
    if (s2g) stage(A, m0, t2, bb, 0);
    if (vw == 4)      { WAITV4; }
    else if (vw == 0) { WAITV0; }
    BAR();
    CLUSTER(1, 0);
    BAR();
  };
  // NOTE: rdA(bb, m, 1) must read rows m4-7 -> fold mhalf into the call:
  #undef CLUSTER

  // re-define rdA usage: rows m*16 with m in 0..7; helper above takes m 0..3
  // and mhalf selects +4 (handled by offset m*2048 + mhalf*8192):
  // (implemented via lambda capture trick below)

  // ---- prologue: tile0 all 4 halves + tile1.B-top + tile1.A-top ----
  stage(A,  m0,       0, 0, 0);
  stage(A,  m0 + 128, 0, 0, 16384);
  stage(Bm, n0,       0, 0, 32768);
  stage(Bm, n0 + 128, 0, 0, 49152);
  stage(Bm, n0,       1, 65536, 32768);
  stage(A,  m0,       1, 65536, 0);
  WAITV4;            // retires tile0's 8 loads; tile1's 4 stay in flight
  BAR();

  #pragma unroll 1
  for (int tp = 0; tp < 3; ++tp) {
    int ta = 2 * tp, tb = 2 * tp + 1;
    tile(0,     ta + 1, ta + 2, true, true, 4);
    tile(65536, tb + 1, tb + 2, true, true, 4);
  }
  tile(0,     7, 8, true,  false, 0);   // tau=6: stage t7.A-bot/B-bot; drain all
  tile(65536, 8, 9, false, false, -1);  // tau=7: pure compute
}

// The rdA(bb, m, mhalf) lambda above ignores mhalf in the address — fix via
// macro: we need rows (mhalf*4+m). Simplest correct approach: dedicated core
// below re-implemented without the dead param. (Kept single definition to
// avoid drift — see core256_fix.)
//
// --- NOTE: to keep one true implementation, core256 above is NOT used. ---

__device__ __forceinline__ void core256b(const ushortT* __restrict__ A,
                                         const ushortT* __restrict__ Bm,
                                         ushortT* lds, int m0, int n0,
                                         float4v (&acc)[8][4]) {
  char* ldsb = (char*)lds;
  const int tid = threadIdx.x;
  const int w = tid >> 6, l = tid & 63;
  const int wm = w >> 2, wn = w & 3;

  const int P0b = tid * 16, P1b = 8192 + tid * 16;
  const int r0 = P0b >> 7, r1 = P1b >> 7;
  const int s0 = (P0b & 127) ^ ((r0 & 7) << 4);
  const int s1 = (P1b & 127) ^ ((r1 & 7) << 4);
  const size_t g0 = (size_t)r0 * 512 + (s0 >> 1);
  const size_t g1 = (size_t)r1 * 512 + (s1 >> 1);
  auto stage = [&](const ushortT* mat, int rowbase, int kt, int bufb, int region) {
    const ushortT* gsrc = mat + (size_t)rowbase * 512 + kt * 64;
    char* dbase = ldsb + bufb + region;
    gl_lds16(gsrc + g0, dbase + P0b);
    gl_lds16(gsrc + g1, dbase + P1b);
  };

  const int colb = (l >> 4) * 16;
  const int cs0 = colb ^ ((l & 7) << 4);
  const int cs1 = (64 + colb) ^ ((l & 7) << 4);
  const int arow = wm * 16384 + (l & 15) * 128;
  const int brow = 32768 + wn * 8192 + (l & 15) * 128;

  short8v Af[4][2], Bf[4][2];

  #define RDA4(bb, MH)                                                  \
    { _Pragma("unroll")                                                 \
      for (int mm = 0; mm < 4; ++mm) {                                  \
        const char* p = ldsb + (bb) + arow + ((MH)*4 + mm) * 2048;      \
        Af[mm][0] = *(const short8v*)(p + cs0);                         \
        Af[mm][1] = *(const short8v*)(p + cs1);                         \
      } }
  #define RDB2(bb, N0)                                                  \
    { _Pragma("unroll")                                                 \
      for (int nn = 0; nn < 2; ++nn) {                                  \
        const char* p = ldsb + (bb) + brow + ((N0) + nn) * 2048;        \
        Bf[(N0)+nn][0] = *(const short8v*)(p + cs0);                    \
        Bf[(N0)+nn][1] = *(const short8v*)(p + cs1);                    \
      } }
  #define CLUSTER(MH, NP)                                               \
    { __builtin_amdgcn_s_setprio(1);                                    \
      _Pragma("unroll")                                                 \
      for (int mm = 0; mm < 4; ++mm) {                                  \
        _Pragma("unroll")                                               \
        for (int nn = 0; nn < 2; ++nn) {                                \
          MFMA16(acc[(MH)*4+mm][(NP)*2+nn], Af[mm][0], Bf[(NP)*2+nn][0]); \
          MFMA16(acc[(MH)*4+mm][(NP)*2+nn], Af[mm][1], Bf[(NP)*2+nn][1]); \
        } }                                                             \
      __builtin_amdgcn_s_setprio(0); }

  auto tile = [&](int bb, int t1, int t2, bool s1g, bool s2g, int vw) {
    // P1
    RDA4(bb, 0); RDB2(bb, 0);
    if (s1g) stage(A, m0 + 128, t1, bb ^ 65536, 16384);
    BAR(); LGKM0;
    CLUSTER(0, 0);
    BAR();
    // P2
    RDB2(bb, 2);
    if (s1g) stage(Bm, n0 + 128, t1, bb ^ 65536, 49152);
    BAR(); LGKM0;
    CLUSTER(0, 1);
    BAR();
    // P3
    RDA4(bb, 1);
    if (s2g) stage(Bm, n0, t2, bb, 32768);
    BAR(); LGKM0;
    CLUSTER(1, 1);
    BAR();
    // P4
    if (s2g) stage(A, m0, t2, bb, 0);
    if (vw == 4)      { WAITV4; }
    else if (vw == 0) { WAITV0; }
    BAR();
    CLUSTER(1, 0);
    BAR();
  };

  // prologue
  stage(A,  m0,       0, 0, 0);
  stage(A,  m0 + 128, 0, 0, 16384);
  stage(Bm, n0,       0, 0, 32768);
  stage(Bm, n0 + 128, 0, 0, 49152);
  stage(Bm, n0,       1, 65536, 32768);
  stage(A,  m0,       1, 65536, 0);
  WAITV4;
  BAR();

  #pragma unroll 1
  for (int tp = 0; tp < 3; ++tp) {
    tile(0,     2 * tp + 1, 2 * tp + 2, true, true, 4);
    tile(65536, 2 * tp + 2, 2 * tp + 3, true, true, 4);
  }
  tile(0,     7, 8, true,  false, 0);
  tile(65536, 8, 9, false, false, -1);
  #undef RDA4
  #undef RDB2
  #undef CLUSTER
}

// ---------------- K3: qkv GEMM (65536 x 1536 x 512) -> bf16 ----------------
__global__ __launch_bounds__(512, 2) void gemm_qkv(const ushortT* __restrict__ h,
                                                   const ushortT* __restrict__ wq,
                                                   const float* __restrict__ bias,
                                                   ushortT* __restrict__ outq) {
  __shared__ ushortT lds[65536];   // 128 KB
  int bid = blockIdx.x;
  int wg = (bid & 7) * 192 + (bid >> 3);         // bijective XCD swizzle
  int m0 = (wg / 6) * 256, n0 = (wg % 6) * 256;  // N fastest
  float4v acc[8][4] = {};
  core256b(h, wq, lds, m0, n0, acc);
  const int tid = threadIdx.x;
  const int w = tid >> 6, l = tid & 63;
  const int wm = w >> 2, wn = w & 3;
  __syncthreads();
  ushortT* es = lds + w * 1280;              // 16 x 72 shorts per wave
  float bb[4];
  #pragma unroll
  for (int fn = 0; fn < 4; ++fn) bb[fn] = bias[n0 + wn * 64 + fn * 16 + (l & 15)];
  int r = l >> 2, g = l & 3;
  #pragma unroll
  for (int fm = 0; fm < 8; ++fm) {
    #pragma unroll
    for (int fn = 0; fn < 4; ++fn)
      #pragma unroll
      for (int j = 0; j < 4; ++j)
        es[((l >> 4) * 4 + j) * 72 + fn * 16 + (l & 15)] = f2bf(acc[fm][fn][j] + bb[fn]);
    uint4 v0 = *(const uint4*)(es + r * 72 + g * 16);
    uint4 v1 = *(const uint4*)(es + r * 72 + g * 16 + 8);
    size_t mrow = (size_t)m0 + wm * 128 + fm * 16 + r;
    uint4* dst = (uint4*)(outq + mrow * 1536 + n0 + wn * 64 + g * 16);
    dst[0] = v0; dst[1] = v1;
  }
}

// ---------------- K4: per-position 8x8 head attention (LDS-free) ----------
__global__ __launch_bounds__(256) void attn_k(const ushortT* __restrict__ qkv,
                                              ushortT* __restrict__ o) {
  int gp = blockIdx.x * 256 + threadIdx.x;
  int pos = gp >> 3, hh = gp & 7;
  const ushortT* base = qkv + (size_t)pos * 1536;
  float q[64];
  #pragma unroll
  for (int i = 0; i < 8; ++i) {
    uint4 u = *(const uint4*)(base + hh * 64 + i * 8);
    float2 t0 = up2(u.x), t1 = up2(u.y), t2 = up2(u.z), t3 = up2(u.w);
    q[i*8+0]=t0.x; q[i*8+1]=t0.y; q[i*8+2]=t1.x; q[i*8+3]=t1.y;
    q[i*8+4]=t2.x; q[i*8+5]=t2.y; q[i*8+6]=t3.x; q[i*8+7]=t3.y;
  }
  float lg[8];
  #pragma unroll
  for (int g = 0; g < 8; ++g) {
    float s = 0.f;
    #pragma unroll
    for (int d8 = 0; d8 < 8; ++d8) {
      uint4 kk = *(const uint4*)(base + 512 + g * 64 + d8 * 8);
      float2 k0 = up2(kk.x), k1 = up2(kk.y), k2 = up2(kk.z), k3 = up2(kk.w);
      s += q[d8*8+0]*k0.x + q[d8*8+1]*k0.y + q[d8*8+2]*k1.x + q[d8*8+3]*k1.y
         + q[d8*8+4]*k2.x + q[d8*8+5]*k2.y + q[d8*8+6]*k3.x + q[d8*8+7]*k3.y;
    }
    lg[g] = s * 0.125f;
  }
  float mx = lg[0];
  #pragma unroll
  for (int g = 1; g < 8; ++g) mx = fmaxf(mx, lg[g]);
  float ssum = 0.f;
  #pragma unroll
  for (int g = 0; g < 8; ++g) { lg[g] = __expf(lg[g] - mx); ssum += lg[g]; }
  float inv = 1.f / ssum;
  #pragma unroll
  for (int g = 0; g < 8; ++g) lg[g] *= inv;
  float oa[64];
  #pragma unroll
  for (int i = 0; i < 64; ++i) oa[i] = 0.f;
  #pragma unroll
  for (int g = 0; g < 8; ++g) {
    float wg = lg[g];
    #pragma unroll
    for (int d8 = 0; d8 < 8; ++d8) {
      uint4 vv = *(const uint4*)(base + 1024 + g * 64 + d8 * 8);
      float2 v0 = up2(vv.x), v1 = up2(vv.y), v2 = up2(vv.z), v3 = up2(vv.w);
      oa[d8*8+0] += wg*v0.x; oa[d8*8+1] += wg*v0.y;
      oa[d8*8+2] += wg*v1.x; oa[d8*8+3] += wg*v1.y;
      oa[d8*8+4] += wg*v2.x; oa[d8*8+5] += wg*v2.y;
      oa[d8*8+6] += wg*v3.x; oa[d8*8+7] += wg*v3.y;
    }
  }
  ushortT* dst = o + (size_t)pos * 512 + hh * 64;
  #pragma unroll
  for (int i = 0; i < 8; ++i) {
    uint4 w_;
    w_.x = (unsigned)f2bf(oa[i*8+0]) | ((unsigned)f2bf(oa[i*8+1]) << 16);
    w_.y = (unsigned)f2bf(oa[i*8+2]) | ((unsigned)f2bf(oa[i*8+3]) << 16);
    w_.z = (unsigned)f2bf(oa[i*8+4]) | ((unsigned)f2bf(oa[i*8+5]) << 16);
    w_.w = (unsigned)f2bf(oa[i*8+6]) | ((unsigned)f2bf(oa[i*8+7]) << 16);
    *(uint4*)(dst + i * 8) = w_;
  }
}

// ---------------- K5: proj GEMM + residual + transposed fp32 write ---------
__global__ __launch_bounds__(512, 2) void gemm_proj(const ushortT* __restrict__ o,
                                                    const ushortT* __restrict__ wp,
                                                    const float* __restrict__ bias,
                                                    const float* __restrict__ x,
                                                    float* __restrict__ out) {
  __shared__ ushortT lds[65536];
  int bid = blockIdx.x;
  int wg = (bid & 7) * 64 + (bid >> 3);
  int m0 = (wg >> 1) * 256, n0 = (wg & 1) * 256;
  float4v acc[8][4] = {};
  core256b(o, wp, lds, m0, n0, acc);
  const int tid = threadIdx.x;
  const int w = tid >> 6, l = tid & 63;
  const int wm = w >> 2, wn = w & 3;
  __syncthreads();
  float* es = (float*)((char*)lds + w * 4608);   // 16 x 68 floats per wave
  int b = m0 >> 12;
  int c = n0 + wn * 64 + l;
  float bc = bias[c];
  const float* xrow = x + ((size_t)b * 512 + c) * 4096;
  float* orow = out + ((size_t)b * 512 + c) * 4096;
  int nb0 = (m0 & 4095) + wm * 128;
  #pragma unroll
  for (int fm = 0; fm < 8; ++fm) {
    #pragma unroll
    for (int fn = 0; fn < 4; ++fn)
      #pragma unroll
      for (int j = 0; j < 4; ++j)
        es[((l >> 4) * 4 + j) * 68 + fn * 16 + (l & 15)] = acc[fm][fn][j];
    int nb = nb0 + fm * 16;
    #pragma unroll
    for (int q4 = 0; q4 < 4; ++q4) {
      float4 xv = *(const float4*)(xrow + nb + q4 * 4);
      float4 ov;
      ov.x = xv.x + bc + es[(q4 * 4 + 0) * 68 + l];
      ov.y = xv.y + bc + es[(q4 * 4 + 1) * 68 + l];
      ov.z = xv.z + bc + es[(q4 * 4 + 2) * 68 + l];
      ov.w = xv.w + bc + es[(q4 * 4 + 3) * 68 + l];
      *(float4*)(orow + nb + q4 * 4) = ov;
    }
  }
}

// ---------------- launcher ----------------
extern "C" void kernel_launch(void* const* d_in, const int* in_sizes, int n_in,
                              void* d_out, int out_size, void* d_ws, size_t ws_size,
                              hipStream_t stream) {
  const float* x     = (const float*)d_in[0];
  const float* nw    = (const float*)d_in[1];
  const float* nb    = (const float*)d_in[2];
  const float* qkvw  = (const float*)d_in[3];
  const float* qkvb  = (const float*)d_in[4];
  const float* pw    = (const float*)d_in[5];
  const float* pb    = (const float*)d_in[6];
  float* out = (float*)d_out;
  char* ws = (char*)d_ws;

  const size_t OFF_WQ   = 4096;
  const size_t OFF_WP   = OFF_WQ + 1572864;
  const size_t OFF_H    = OFF_WP + 524288;
  const size_t OFF_QKV  = OFF_H + 67108864;

  float2* stats   = (float2*)ws;
  ushortT* wq_b   = (ushortT*)(ws + OFF_WQ);
  ushortT* wp_b   = (ushortT*)(ws + OFF_WP);
  ushortT* h      = (ushortT*)(ws + OFF_H);
  ushortT* qkv    = (ushortT*)(ws + OFF_QKV);

  wconv<<<768, 256, 0, stream>>>(qkvw, wq_b, 786432);
  wconv<<<256, 256, 0, stream>>>(pw,   wp_b, 262144);
  gn_stats<<<512, 256, 0, stream>>>(x, stats);
  norm_tr<<<dim3(64, 8, 16), dim3(64, 8), 0, stream>>>(x, nw, nb, stats, h);
  gemm_qkv<<<1536, 512, 0, stream>>>(h, wq_b, qkvb, qkv);
  attn_k<<<2048, 256, 0, stream>>>(qkv, h);
  gemm_proj<<<512, 512, 0, stream>>>(h, wp_b, pb, x, out);
}